// Round 3
// baseline (503.467 us; speedup 1.0000x reference)
//
#include <hip/hip_runtime.h>
#include <cmath>

#define H    512
#define H2   1024
#define V    50000
#define SEQ  400
#define EXT  (V + SEQ)   // 50400
#define NB_V 782         // ceil(50048/64); 782*64 = 50048 >= V

typedef __attribute__((ext_vector_type(8))) short short8;
typedef __attribute__((ext_vector_type(4))) float floatx4;

__device__ __forceinline__ unsigned int bfpack2(float lo, float hi) {
    unsigned int a = __float_as_uint(lo) + 0x8000u;   // round-half-up
    unsigned int b = __float_as_uint(hi) + 0x8000u;
    return __builtin_amdgcn_perm(b, a, 0x07060302);   // {hi.b3,hi.b2,lo.b3,lo.b2}
}
__device__ __forceinline__ uint4 pack8(float4 a, float4 b) {
    uint4 r;
    r.x = bfpack2(a.x, a.y);
    r.y = bfpack2(a.z, a.w);
    r.z = bfpack2(b.x, b.y);
    r.w = bfpack2(b.z, b.w);
    return r;
}
__device__ __forceinline__ float4 ld4(const float* p) { return *(const float4*)p; }

// ---------------------------------------------------------------------------
// K01 fused: blocks [0,64)  = GRU gate partials
//            blocks [64,192)= Wh/Ws transpose->bf16
// ---------------------------------------------------------------------------
__global__ __launch_bounds__(256) void k01_fused(
    const float* __restrict__ x, const float* __restrict__ h0,
    const float* __restrict__ W_ih, const float* __restrict__ W_hh,
    float* __restrict__ gacc,
    const float* __restrict__ Wh, const float* __restrict__ Ws,
    unsigned short* __restrict__ WhT, unsigned short* __restrict__ WsT)
{
    __shared__ __align__(16) unsigned char smem[65536];
    const int tid = threadIdx.x;

    if (blockIdx.x >= 64) {
        // ---- transpose branch ----
        float (*T)[65] = (float (*)[65])smem;          // 64*65*4 = 16.6 KB
        const int e   = blockIdx.x - 64;
        const int zz  = e >> 6, rem = e & 63;
        const int k0  = (rem & 7) * 64, n0 = (rem >> 3) * 64;
        const float* src = zz ? Ws : Wh;
        unsigned short* dst = zz ? WsT : WhT;
        #pragma unroll
        for (int i = 0; i < 16; ++i) {
            int ee = i * 256 + tid;
            int r = ee >> 6, c = ee & 63;
            T[r][c] = src[(size_t)(k0 + r) * H + n0 + c];
        }
        __syncthreads();
        #pragma unroll
        for (int i = 0; i < 16; ++i) {
            int ee = i * 256 + tid;
            int nn = ee >> 6, kk = ee & 63;
            unsigned int u = __float_as_uint(T[kk][nn]) + 0x8000u;
            dst[(size_t)(n0 + nn) * H + k0 + kk] = (unsigned short)(u >> 16);
        }
        return;
    }

    // ---- GRU partials branch ----
    uint4* Ax = (uint4*)smem;                       // 512 uint4 = 8 KB
    uint4* Ah = (uint4*)(smem + 8192);              // 8 KB
    uint4 (*Bg)[512] = (uint4 (*)[512])(smem + 16384);  // 6 x 8 KB
    const int wave = tid >> 6, lane = tid & 63;
    const int lrow = lane & 15, q = lane >> 4;
    const int jb = blockIdx.x & 7, ks = blockIdx.x >> 3;
    const int J0 = jb * 64;
    const int kc = ks * 64;

    #pragma unroll
    for (int c = 0; c < 2; ++c) {
        int idx = c * 256 + tid;
        int m = idx >> 3, j2 = idx & 7, k8 = j2 ^ (m & 7);
        const float* sx = x  + m * H + kc + k8 * 8;
        const float* sh = h0 + m * H + kc + k8 * 8;
        Ax[idx] = pack8(ld4(sx), ld4(sx + 4));
        Ah[idx] = pack8(ld4(sh), ld4(sh + 4));
    }
    #pragma unroll
    for (int g = 0; g < 6; ++g) {
        const float* Wb = (g < 3) ? W_ih : W_hh;
        const int go = (g % 3) * H;
        #pragma unroll
        for (int c = 0; c < 2; ++c) {
            int idx = c * 256 + tid;
            int n = idx >> 3, j2 = idx & 7, k8 = j2 ^ (n & 7);
            const float* sw = Wb + (size_t)(go + J0 + n) * H + kc + k8 * 8;
            Bg[g][idx] = pack8(ld4(sw), ld4(sw + 4));
        }
    }
    __syncthreads();

    floatx4 accm[6][4];
    #pragma unroll
    for (int g = 0; g < 6; ++g)
        #pragma unroll
        for (int mt = 0; mt < 4; ++mt) accm[g][mt] = (floatx4){0.f, 0.f, 0.f, 0.f};

    #pragma unroll
    for (int kk8 = 0; kk8 < 8; kk8 += 4) {
        const int k8 = kk8 + q;
        short8 ax[4], ah[4];
        #pragma unroll
        for (int mt = 0; mt < 4; ++mt) {
            int m = mt * 16 + lrow;
            ax[mt] = *(const short8*)&Ax[m * 8 + (k8 ^ (m & 7))];
            ah[mt] = *(const short8*)&Ah[m * 8 + (k8 ^ (m & 7))];
        }
        const int n = wave * 16 + lrow;
        const int gidx = n * 8 + (k8 ^ (n & 7));
        #pragma unroll
        for (int g = 0; g < 6; ++g) {
            short8 bb = *(const short8*)&Bg[g][gidx];
            #pragma unroll
            for (int mt = 0; mt < 4; ++mt)
                accm[g][mt] = __builtin_amdgcn_mfma_f32_16x16x32_bf16(
                    (g < 3) ? ax[mt] : ah[mt], bb, accm[g][mt], 0, 0, 0);
        }
    }
    const int j = J0 + wave * 16 + lrow;
    #pragma unroll
    for (int g = 0; g < 6; ++g)
        #pragma unroll
        for (int mt = 0; mt < 4; ++mt)
            #pragma unroll
            for (int r = 0; r < 4; ++r) {
                const int bb = mt * 16 + q * 4 + r;
                gacc[(((size_t)g * 8 + ks) * 64 + bb) * H + j] = accm[g][mt][r];
            }
}

// ---------------------------------------------------------------------------
// K1b: reduce k-slices, apply GRU gate math.  (unchanged)
// ---------------------------------------------------------------------------
__global__ __launch_bounds__(256) void k1_gru_fin(
    const float* __restrict__ gacc, const float* __restrict__ h0,
    const float* __restrict__ b_ih, const float* __restrict__ b_hh,
    float* __restrict__ h_out)
{
    const int e = blockIdx.x * 256 + threadIdx.x;
    const int j = e & (H - 1);
    const int b = e >> 9;
    float gs[6];
    #pragma unroll
    for (int g = 0; g < 6; ++g) {
        float sum = 0.f;
        #pragma unroll
        for (int ks = 0; ks < 8; ++ks)
            sum += gacc[(((size_t)g * 8 + ks) * 64 + b) * H + j];
        gs[g] = sum;
    }
    float rg = 1.f / (1.f + expf(-(gs[0] + b_ih[j] + gs[3] + b_hh[j])));
    float zg = 1.f / (1.f + expf(-(gs[1] + b_ih[H + j] + gs[4] + b_hh[H + j])));
    float ng = tanhf(gs[2] + b_ih[2 * H + j] + rg * (gs[5] + b_hh[2 * H + j]));
    float h0v = h0[b * H + j];
    h_out[b * H + j] = (1.f - zg) * ng + zg * h0v;
}

// ---------------------------------------------------------------------------
// K2 (MFMA): x2 = h @ Ws + b_attn.  (unchanged)
// ---------------------------------------------------------------------------
__global__ __launch_bounds__(256) void k2_x2(
    const float* __restrict__ h, const unsigned short* __restrict__ WsT,
    const float* __restrict__ b_attn, float* __restrict__ x2)
{
    __shared__ uint4 Ag[512];
    __shared__ uint4 Bgg[512];
    const int tid  = threadIdx.x;
    const int wave = tid >> 6, lane = tid & 63;
    const int lrow = lane & 15, q = lane >> 4;
    const int n0   = blockIdx.x * 64;

    floatx4 acc[4];
    #pragma unroll
    for (int mt = 0; mt < 4; ++mt) acc[mt] = (floatx4){0.f, 0.f, 0.f, 0.f};

    for (int kc = 0; kc < H; kc += 64) {
        __syncthreads();
        #pragma unroll
        for (int c = 0; c < 2; ++c) {
            int idx = c * 256 + tid;
            int m = idx >> 3, j2 = idx & 7, k8 = j2 ^ (m & 7);
            const float* sh = h + m * H + kc + k8 * 8;
            Ag[idx] = pack8(ld4(sh), ld4(sh + 4));
            Bgg[idx] = *(const uint4*)(WsT + (size_t)(n0 + m) * H + kc + k8 * 8);
        }
        __syncthreads();
        #pragma unroll
        for (int kk8 = 0; kk8 < 8; kk8 += 4) {
            const int k8 = kk8 + q;
            const int n = wave * 16 + lrow;
            short8 bb = *(const short8*)&Bgg[n * 8 + (k8 ^ (n & 7))];
            #pragma unroll
            for (int mt = 0; mt < 4; ++mt) {
                int m = mt * 16 + lrow;
                short8 a = *(const short8*)&Ag[m * 8 + (k8 ^ (m & 7))];
                acc[mt] = __builtin_amdgcn_mfma_f32_16x16x32_bf16(a, bb, acc[mt], 0, 0, 0);
            }
        }
    }
    const int n = n0 + wave * 16 + lrow;
    const float ba = b_attn[n];
    #pragma unroll
    for (int mt = 0; mt < 4; ++mt)
        #pragma unroll
        for (int r = 0; r < 4; ++r) {
            const int bb = mt * 16 + q * 4 + r;
            x2[bb * H + n] = acc[mt][r] + ba;
        }
}

// ---------------------------------------------------------------------------
// K3 v7: N=512 per block (grid 400, ONE pass over enc -- 52.4 MB HBM instead
// of 105 MB).  LDS 73 KB (A 8 + B 64 + red 1) -> 2 blocks/CU (146<160).
// Inner loop loads ONE B-fragment at a time (reused by 4 mt MFMAs) to keep
// VGPR ~180 (acc[4][8]=128) below the 256 cliff.
// ---------------------------------------------------------------------------
__global__ __launch_bounds__(256) void k3_scores(
    const float* __restrict__ enc, const unsigned short* __restrict__ WhT,
    const float* __restrict__ x2, const float* __restrict__ v,
    float* __restrict__ part)
{
    __shared__ uint4 AsG[512];     // 64 m  x 8 kg  (8 KB)
    __shared__ uint4 BsG[4096];    // 512 n x 8 kg  (64 KB)
    __shared__ float red[256];
    const int s    = blockIdx.x;
    const int tid  = threadIdx.x;
    const int wave = tid >> 6, lane = tid & 63;
    const int lrow = lane & 15, q = lane >> 4;

    floatx4 acc[4][8];
    #pragma unroll
    for (int mt = 0; mt < 4; ++mt)
        #pragma unroll
        for (int nt = 0; nt < 8; ++nt) acc[mt][nt] = (floatx4){0.f, 0.f, 0.f, 0.f};

    const float* Abase = enc + (size_t)s * 64 * H;
    for (int kc = 0; kc < H; kc += 64) {
        __syncthreads();
        #pragma unroll
        for (int c = 0; c < 2; ++c) {
            int idx = c * 256 + tid;
            int m = idx >> 3, k8 = (idx & 7) ^ (m & 7);
            const float* sa = Abase + m * H + kc + k8 * 8;
            AsG[idx] = pack8(ld4(sa), ld4(sa + 4));
        }
        #pragma unroll
        for (int c = 0; c < 16; ++c) {
            int idx = c * 256 + tid;
            int n = idx >> 3, k8 = (idx & 7) ^ (n & 7);
            BsG[idx] = *(const uint4*)(WhT + (size_t)n * H + kc + k8 * 8);
        }
        __syncthreads();
        #pragma unroll
        for (int kk8 = 0; kk8 < 8; kk8 += 4) {
            const int k8 = kk8 + q;
            short8 a[4];
            #pragma unroll
            for (int mt = 0; mt < 4; ++mt) {
                int m = mt * 16 + lrow;
                a[mt] = *(const short8*)&AsG[m * 8 + (k8 ^ (m & 7))];
            }
            #pragma unroll
            for (int nt = 0; nt < 8; ++nt) {
                int n = wave * 128 + nt * 16 + lrow;
                short8 bb = *(const short8*)&BsG[n * 8 + (k8 ^ (n & 7))];
                #pragma unroll
                for (int mt = 0; mt < 4; ++mt)
                    acc[mt][nt] = __builtin_amdgcn_mfma_f32_16x16x32_bf16(
                        a[mt], bb, acc[mt][nt], 0, 0, 0);
            }
        }
    }
    float val[4][4];
    #pragma unroll
    for (int mt = 0; mt < 4; ++mt) {
        #pragma unroll
        for (int r = 0; r < 4; ++r) {
            const int bb = mt * 16 + q * 4 + r;
            float sum = 0.f;
            #pragma unroll
            for (int nt = 0; nt < 8; ++nt) {
                const int n = wave * 128 + nt * 16 + lrow;
                sum += tanhf(acc[mt][nt][r] + x2[bb * H + n]) * v[n];
            }
            #pragma unroll
            for (int off = 8; off > 0; off >>= 1) sum += __shfl_down(sum, off, 16);
            val[mt][r] = sum;
        }
    }
    __syncthreads();
    if (lrow == 0) {
        #pragma unroll
        for (int mt = 0; mt < 4; ++mt)
            #pragma unroll
            for (int r = 0; r < 4; ++r)
                red[wave * 64 + mt * 16 + q * 4 + r] = val[mt][r];
    }
    __syncthreads();
    if (tid < 64) {
        float sc = red[tid] + red[64 + tid] + red[128 + tid] + red[192 + tid];
        part[(size_t)s * 64 + tid] = sc;
    }
}

// ---------------------------------------------------------------------------
// K45 fused: per-(b,sg) block recomputes the 400-wide softmax redundantly,
// sg==0 writes attn; then float4-vectorized context partial (50 s rows).
// part is now a single segment (k3 writes full scores).
// grid (64 b, 8 sg), 128 threads.
// ---------------------------------------------------------------------------
__global__ __launch_bounds__(128) void k45_ctx(
    const float* __restrict__ part, const float* __restrict__ enc,
    float* __restrict__ attn_out, float* __restrict__ ctxp)
{
    const int b  = blockIdx.x;
    const int sg = blockIdx.y;
    const int t  = threadIdx.x;
    __shared__ float a_all[SEQ];
    __shared__ float red2[2];
    __shared__ float smax, ssum;

    // softmax over all 400 s for this b
    float mv[4];
    float mx = -1e30f;
    #pragma unroll
    for (int i = 0; i < 4; ++i) {
        int s = i * 128 + t;
        if (s < SEQ) {
            float vv = part[(size_t)s * 64 + b];
            mv[i] = vv;
            mx = fmaxf(mx, vv);
        }
    }
    #pragma unroll
    for (int off = 32; off > 0; off >>= 1) mx = fmaxf(mx, __shfl_down(mx, off, 64));
    if ((t & 63) == 0) red2[t >> 6] = mx;
    __syncthreads();
    if (t == 0) smax = fmaxf(red2[0], red2[1]);
    __syncthreads();
    float ev[4];
    float se = 0.f;
    #pragma unroll
    for (int i = 0; i < 4; ++i) {
        int s = i * 128 + t;
        if (s < SEQ) { ev[i] = expf(mv[i] - smax); se += ev[i]; }
    }
    #pragma unroll
    for (int off = 32; off > 0; off >>= 1) se += __shfl_down(se, off, 64);
    if ((t & 63) == 0) red2[t >> 6] = se;
    __syncthreads();
    if (t == 0) ssum = red2[0] + red2[1];
    __syncthreads();
    const float inv = 1.f / ssum;
    #pragma unroll
    for (int i = 0; i < 4; ++i) {
        int s = i * 128 + t;
        if (s < SEQ) {
            float av = ev[i] * inv;
            a_all[s] = av;
            if (sg == 0) attn_out[s * 64 + b] = av;
        }
    }
    __syncthreads();

    // context partial: 50 s rows, thread owns 4 consecutive h cols
    const int hh = 4 * t;
    const float* p = enc + ((size_t)(sg * 50) * 64 + b) * H + hh;
    float4 a0 = {0.f, 0.f, 0.f, 0.f}, a1 = {0.f, 0.f, 0.f, 0.f};
    #pragma unroll 5
    for (int i = 0; i < 50; i += 2) {
        float4 e0 = *(const float4*)p;
        float4 e1 = *(const float4*)(p + (size_t)64 * H);
        float w0 = a_all[sg * 50 + i];
        float w1 = a_all[sg * 50 + i + 1];
        a0.x += w0 * e0.x; a0.y += w0 * e0.y; a0.z += w0 * e0.z; a0.w += w0 * e0.w;
        a1.x += w1 * e1.x; a1.y += w1 * e1.y; a1.z += w1 * e1.z; a1.w += w1 * e1.w;
        p += (size_t)128 * H;
    }
    float4 r;
    r.x = a0.x + a1.x; r.y = a0.y + a1.y; r.z = a0.z + a1.z; r.w = a0.w + a1.w;
    *(float4*)&ctxp[((size_t)sg * 64 + b) * H + hh] = r;
}

// ---------------------------------------------------------------------------
// K5b: reduce 8 ctx partials; p = sigmoid(...); emit bf16 global_state.
// ---------------------------------------------------------------------------
__global__ __launch_bounds__(512) void k5b_p(
    const float* __restrict__ ctxp, const float* __restrict__ pWh,
    const float* __restrict__ hdec, const float* __restrict__ pWs,
    const float* __restrict__ x, const float* __restrict__ pWx,
    const float* __restrict__ pWx_b,
    float* __restrict__ p_out, float* __restrict__ p_ws,
    unsigned short* __restrict__ gsb)
{
    const int b = blockIdx.x;
    const int t = threadIdx.x;
    __shared__ float rbuf[8];
    float c = 0.f;
    #pragma unroll
    for (int sg = 0; sg < 8; ++sg)
        c += ctxp[((size_t)sg * 64 + b) * H + t];
    float hv = hdec[b * H + t];
    gsb[(size_t)b * H2 + t]     = (unsigned short)((__float_as_uint(hv) + 0x8000u) >> 16);
    gsb[(size_t)b * H2 + H + t] = (unsigned short)((__float_as_uint(c)  + 0x8000u) >> 16);
    float term = c * pWh[t] + hv * pWs[t] + x[b * H + t] * pWx[t];
    #pragma unroll
    for (int off = 32; off > 0; off >>= 1) term += __shfl_down(term, off, 64);
    if ((t & 63) == 0) rbuf[t >> 6] = term;
    __syncthreads();
    if (t == 0) {
        float ssv = pWx_b[0];
        #pragma unroll
        for (int w = 0; w < 8; ++w) ssv += rbuf[w];
        float pv = 1.f / (1.f + expf(-ssv));
        p_out[b] = pv;
        p_ws[b]  = pv;
    }
}

// ---------------------------------------------------------------------------
// K6: N=64 per block, grid 782 (+100 oov blocks).  (unchanged)
// ---------------------------------------------------------------------------
__global__ __launch_bounds__(256) void k6_vocab(
    const unsigned short* __restrict__ gsb, const float* __restrict__ outW,
    const float* __restrict__ outb, const float* __restrict__ p_ws,
    const float* __restrict__ attn, const int* __restrict__ mask,
    float* __restrict__ ext)
{
    const int tid = threadIdx.x;
    if (blockIdx.x >= NB_V) {
        int e = (blockIdx.x - NB_V) * 256 + tid;
        int s = e >> 6, b = e & 63;
        float val = (1.f - p_ws[b]) * attn[e] * (mask[e] ? 1.f : 0.f);
        ext[(size_t)b * EXT + V + s] = val;
        return;
    }
    __shared__ uint4 AsG[512];    // 64 b x 8 kg (bf16)
    __shared__ uint4 BsG[512];    // 64 v x 8 kg
    __shared__ float p_l[64];
    const int wave = tid >> 6, lane = tid & 63;
    const int lrow = lane & 15, q = lane >> 4;
    const int v0   = blockIdx.x * 64;

    if (tid < 64) p_l[tid] = p_ws[tid];

    floatx4 acc[4];
    #pragma unroll
    for (int mt = 0; mt < 4; ++mt) acc[mt] = (floatx4){0.f, 0.f, 0.f, 0.f};

    for (int kc = 0; kc < H2; kc += 64) {
        __syncthreads();
        #pragma unroll
        for (int c = 0; c < 2; ++c) {           // global_state tile (bf16 copy)
            int idx = c * 256 + tid;
            int m = idx >> 3, k8 = (idx & 7) ^ (m & 7);
            AsG[idx] = *(const uint4*)(gsb + (size_t)m * H2 + kc + k8 * 8);
        }
        #pragma unroll
        for (int c = 0; c < 2; ++c) {           // out_W tile (64 rows)
            int idx = c * 256 + tid;
            int n = idx >> 3, k8 = (idx & 7) ^ (n & 7);
            int vr = v0 + n; if (vr >= V) vr = V - 1;
            const float* sb = outW + (size_t)vr * H2 + kc + k8 * 8;
            BsG[idx] = pack8(ld4(sb), ld4(sb + 4));
        }
        __syncthreads();
        #pragma unroll
        for (int kk8 = 0; kk8 < 8; kk8 += 4) {
            const int k8 = kk8 + q;
            const int n = wave * 16 + lrow;
            short8 bb = *(const short8*)&BsG[n * 8 + (k8 ^ (n & 7))];
            #pragma unroll
            for (int mt = 0; mt < 4; ++mt) {
                int m = mt * 16 + lrow;
                short8 a = *(const short8*)&AsG[m * 8 + (k8 ^ (m & 7))];
                acc[mt] = __builtin_amdgcn_mfma_f32_16x16x32_bf16(a, bb, acc[mt], 0, 0, 0);
            }
        }
    }
    const int n = v0 + wave * 16 + lrow;
    if (n < V) {
        const float ob = outb[n];
        #pragma unroll
        for (int mt = 0; mt < 4; ++mt) {
            #pragma unroll
            for (int r = 0; r < 4; ++r) {
                const int bb = mt * 16 + q * 4 + r;
                float zz = acc[mt][r] + ob;
                float sv = (zz > 0.f) ? 1.0507009873554805f * zz
                                      : 1.7580993408473766f * (expf(zz) - 1.f);
                ext[(size_t)bb * EXT + n] = p_l[bb] * sv;
            }
        }
    }
}

// ---------------------------------------------------------------------------
extern "C" void kernel_launch(void* const* d_in, const int* in_sizes, int n_in,
                              void* d_out, int out_size, void* d_ws, size_t ws_size,
                              hipStream_t stream)
{
    (void)in_sizes; (void)n_in; (void)out_size; (void)ws_size;
    const float* x      = (const float*)d_in[0];
    const float* enc    = (const float*)d_in[1];
    const int*   mask   = (const int*)  d_in[2];
    const float* h0     = (const float*)d_in[3];
    const float* W_ih   = (const float*)d_in[4];
    const float* W_hh   = (const float*)d_in[5];
    const float* b_ih   = (const float*)d_in[6];
    const float* b_hh   = (const float*)d_in[7];
    const float* outW   = (const float*)d_in[8];
    const float* outb   = (const float*)d_in[9];
    const float* v      = (const float*)d_in[10];
    const float* Wh     = (const float*)d_in[11];
    const float* Ws     = (const float*)d_in[12];
    const float* b_attn = (const float*)d_in[13];
    const float* pWh    = (const float*)d_in[14];
    const float* pWs    = (const float*)d_in[15];
    const float* pWx    = (const float*)d_in[16];
    const float* pWx_b  = (const float*)d_in[17];

    float* out        = (float*)d_out;
    float* out_ext    = out;                           // 64 x 50400
    float* out_hidden = out + (size_t)64 * EXT;        // 64 x 512
    float* out_p      = out_hidden + 64 * H;           // 64
    float* out_attn   = out_p + 64;                    // 400 x 64

    float* ws       = (float*)d_ws;
    float* ws_x2    = ws;                              // 64*512
    float* ws_part  = ws_x2 + 64 * H;                  // 400*64 (single segment)
    float* ws_ctxp  = ws_part + 4 * SEQ * 64;          // 8*64*512
    float* ws_p     = ws_ctxp + 8 * 64 * H;            // 64
    float* ws_gacc  = ws_p + 64;                       // 6*8*64*512 (6.3MB)
    unsigned short* ws_whT = (unsigned short*)(ws_gacc + 6 * 8 * 64 * H);
    unsigned short* ws_wsT = ws_whT + (size_t)H * H;
    unsigned short* ws_gsb = ws_wsT + (size_t)H * H;   // 64 x 1024 bf16

    k01_fused<<<192, 256, 0, stream>>>(x, h0, W_ih, W_hh, ws_gacc,
                                       Wh, Ws, ws_whT, ws_wsT);
    k1_gru_fin<<<128, 256, 0, stream>>>(ws_gacc, h0, b_ih, b_hh, out_hidden);
    k2_x2<<<8, 256, 0, stream>>>(out_hidden, ws_wsT, b_attn, ws_x2);
    k3_scores<<<SEQ, 256, 0, stream>>>(enc, ws_whT, ws_x2, v, ws_part);
    k45_ctx<<<dim3(64, 8), 128, 0, stream>>>(ws_part, enc, out_attn, ws_ctxp);
    k5b_p<<<64, 512, 0, stream>>>(ws_ctxp, pWh, out_hidden, pWs, x, pWx, pWx_b,
                                  out_p, ws_p, ws_gsb);
    k6_vocab<<<NB_V + 100, 256, 0, stream>>>(ws_gsb, outW, outb, ws_p,
                                             out_attn, mask, out_ext);
}

// Round 4
// 453.907 us; speedup vs baseline: 1.1092x; 1.1092x over previous
//
#include <hip/hip_runtime.h>
#include <cmath>

#define H    512
#define H2   1024
#define V    50000
#define SEQ  400
#define EXT  (V + SEQ)   // 50400
#define NB_V 782         // ceil(50048/64); 782*64 = 50048 >= V

typedef __attribute__((ext_vector_type(8))) short short8;
typedef __attribute__((ext_vector_type(4))) float floatx4;

__device__ __forceinline__ unsigned int bfpack2(float lo, float hi) {
    unsigned int a = __float_as_uint(lo) + 0x8000u;   // round-half-up
    unsigned int b = __float_as_uint(hi) + 0x8000u;
    return __builtin_amdgcn_perm(b, a, 0x07060302);   // {hi.b3,hi.b2,lo.b3,lo.b2}
}
__device__ __forceinline__ uint4 pack8(float4 a, float4 b) {
    uint4 r;
    r.x = bfpack2(a.x, a.y);
    r.y = bfpack2(a.z, a.w);
    r.z = bfpack2(b.x, b.y);
    r.w = bfpack2(b.z, b.w);
    return r;
}
__device__ __forceinline__ float4 ld4(const float* p) { return *(const float4*)p; }

// ---------------------------------------------------------------------------
// K01 fused: blocks [0,64)  = GRU gate partials
//            blocks [64,192)= Wh/Ws transpose->bf16
// ---------------------------------------------------------------------------
__global__ __launch_bounds__(256) void k01_fused(
    const float* __restrict__ x, const float* __restrict__ h0,
    const float* __restrict__ W_ih, const float* __restrict__ W_hh,
    float* __restrict__ gacc,
    const float* __restrict__ Wh, const float* __restrict__ Ws,
    unsigned short* __restrict__ WhT, unsigned short* __restrict__ WsT)
{
    __shared__ __align__(16) unsigned char smem[65536];
    const int tid = threadIdx.x;

    if (blockIdx.x >= 64) {
        // ---- transpose branch ----
        float (*T)[65] = (float (*)[65])smem;          // 64*65*4 = 16.6 KB
        const int e   = blockIdx.x - 64;
        const int zz  = e >> 6, rem = e & 63;
        const int k0  = (rem & 7) * 64, n0 = (rem >> 3) * 64;
        const float* src = zz ? Ws : Wh;
        unsigned short* dst = zz ? WsT : WhT;
        #pragma unroll
        for (int i = 0; i < 16; ++i) {
            int ee = i * 256 + tid;
            int r = ee >> 6, c = ee & 63;
            T[r][c] = src[(size_t)(k0 + r) * H + n0 + c];
        }
        __syncthreads();
        #pragma unroll
        for (int i = 0; i < 16; ++i) {
            int ee = i * 256 + tid;
            int nn = ee >> 6, kk = ee & 63;
            unsigned int u = __float_as_uint(T[kk][nn]) + 0x8000u;
            dst[(size_t)(n0 + nn) * H + k0 + kk] = (unsigned short)(u >> 16);
        }
        return;
    }

    // ---- GRU partials branch ----
    uint4* Ax = (uint4*)smem;                       // 512 uint4 = 8 KB
    uint4* Ah = (uint4*)(smem + 8192);              // 8 KB
    uint4 (*Bg)[512] = (uint4 (*)[512])(smem + 16384);  // 6 x 8 KB
    const int wave = tid >> 6, lane = tid & 63;
    const int lrow = lane & 15, q = lane >> 4;
    const int jb = blockIdx.x & 7, ks = blockIdx.x >> 3;
    const int J0 = jb * 64;
    const int kc = ks * 64;

    #pragma unroll
    for (int c = 0; c < 2; ++c) {
        int idx = c * 256 + tid;
        int m = idx >> 3, j2 = idx & 7, k8 = j2 ^ (m & 7);
        const float* sx = x  + m * H + kc + k8 * 8;
        const float* sh = h0 + m * H + kc + k8 * 8;
        Ax[idx] = pack8(ld4(sx), ld4(sx + 4));
        Ah[idx] = pack8(ld4(sh), ld4(sh + 4));
    }
    #pragma unroll
    for (int g = 0; g < 6; ++g) {
        const float* Wb = (g < 3) ? W_ih : W_hh;
        const int go = (g % 3) * H;
        #pragma unroll
        for (int c = 0; c < 2; ++c) {
            int idx = c * 256 + tid;
            int n = idx >> 3, j2 = idx & 7, k8 = j2 ^ (n & 7);
            const float* sw = Wb + (size_t)(go + J0 + n) * H + kc + k8 * 8;
            Bg[g][idx] = pack8(ld4(sw), ld4(sw + 4));
        }
    }
    __syncthreads();

    floatx4 accm[6][4];
    #pragma unroll
    for (int g = 0; g < 6; ++g)
        #pragma unroll
        for (int mt = 0; mt < 4; ++mt) accm[g][mt] = (floatx4){0.f, 0.f, 0.f, 0.f};

    #pragma unroll
    for (int kk8 = 0; kk8 < 8; kk8 += 4) {
        const int k8 = kk8 + q;
        short8 ax[4], ah[4];
        #pragma unroll
        for (int mt = 0; mt < 4; ++mt) {
            int m = mt * 16 + lrow;
            ax[mt] = *(const short8*)&Ax[m * 8 + (k8 ^ (m & 7))];
            ah[mt] = *(const short8*)&Ah[m * 8 + (k8 ^ (m & 7))];
        }
        const int n = wave * 16 + lrow;
        const int gidx = n * 8 + (k8 ^ (n & 7));
        #pragma unroll
        for (int g = 0; g < 6; ++g) {
            short8 bb = *(const short8*)&Bg[g][gidx];
            #pragma unroll
            for (int mt = 0; mt < 4; ++mt)
                accm[g][mt] = __builtin_amdgcn_mfma_f32_16x16x32_bf16(
                    (g < 3) ? ax[mt] : ah[mt], bb, accm[g][mt], 0, 0, 0);
        }
    }
    const int j = J0 + wave * 16 + lrow;
    #pragma unroll
    for (int g = 0; g < 6; ++g)
        #pragma unroll
        for (int mt = 0; mt < 4; ++mt)
            #pragma unroll
            for (int r = 0; r < 4; ++r) {
                const int bb = mt * 16 + q * 4 + r;
                gacc[(((size_t)g * 8 + ks) * 64 + bb) * H + j] = accm[g][mt][r];
            }
}

// ---------------------------------------------------------------------------
// K1b: reduce k-slices, apply GRU gate math.  (unchanged)
// ---------------------------------------------------------------------------
__global__ __launch_bounds__(256) void k1_gru_fin(
    const float* __restrict__ gacc, const float* __restrict__ h0,
    const float* __restrict__ b_ih, const float* __restrict__ b_hh,
    float* __restrict__ h_out)
{
    const int e = blockIdx.x * 256 + threadIdx.x;
    const int j = e & (H - 1);
    const int b = e >> 9;
    float gs[6];
    #pragma unroll
    for (int g = 0; g < 6; ++g) {
        float sum = 0.f;
        #pragma unroll
        for (int ks = 0; ks < 8; ++ks)
            sum += gacc[(((size_t)g * 8 + ks) * 64 + b) * H + j];
        gs[g] = sum;
    }
    float rg = 1.f / (1.f + expf(-(gs[0] + b_ih[j] + gs[3] + b_hh[j])));
    float zg = 1.f / (1.f + expf(-(gs[1] + b_ih[H + j] + gs[4] + b_hh[H + j])));
    float ng = tanhf(gs[2] + b_ih[2 * H + j] + rg * (gs[5] + b_hh[2 * H + j]));
    float h0v = h0[b * H + j];
    h_out[b * H + j] = (1.f - zg) * ng + zg * h0v;
}

// ---------------------------------------------------------------------------
// K2 (MFMA): x2 = h @ Ws + b_attn.  (unchanged)
// ---------------------------------------------------------------------------
__global__ __launch_bounds__(256) void k2_x2(
    const float* __restrict__ h, const unsigned short* __restrict__ WsT,
    const float* __restrict__ b_attn, float* __restrict__ x2)
{
    __shared__ uint4 Ag[512];
    __shared__ uint4 Bgg[512];
    const int tid  = threadIdx.x;
    const int wave = tid >> 6, lane = tid & 63;
    const int lrow = lane & 15, q = lane >> 4;
    const int n0   = blockIdx.x * 64;

    floatx4 acc[4];
    #pragma unroll
    for (int mt = 0; mt < 4; ++mt) acc[mt] = (floatx4){0.f, 0.f, 0.f, 0.f};

    for (int kc = 0; kc < H; kc += 64) {
        __syncthreads();
        #pragma unroll
        for (int c = 0; c < 2; ++c) {
            int idx = c * 256 + tid;
            int m = idx >> 3, j2 = idx & 7, k8 = j2 ^ (m & 7);
            const float* sh = h + m * H + kc + k8 * 8;
            Ag[idx] = pack8(ld4(sh), ld4(sh + 4));
            Bgg[idx] = *(const uint4*)(WsT + (size_t)(n0 + m) * H + kc + k8 * 8);
        }
        __syncthreads();
        #pragma unroll
        for (int kk8 = 0; kk8 < 8; kk8 += 4) {
            const int k8 = kk8 + q;
            const int n = wave * 16 + lrow;
            short8 bb = *(const short8*)&Bgg[n * 8 + (k8 ^ (n & 7))];
            #pragma unroll
            for (int mt = 0; mt < 4; ++mt) {
                int m = mt * 16 + lrow;
                short8 a = *(const short8*)&Ag[m * 8 + (k8 ^ (m & 7))];
                acc[mt] = __builtin_amdgcn_mfma_f32_16x16x32_bf16(a, bb, acc[mt], 0, 0, 0);
            }
        }
    }
    const int n = n0 + wave * 16 + lrow;
    const float ba = b_attn[n];
    #pragma unroll
    for (int mt = 0; mt < 4; ++mt)
        #pragma unroll
        for (int r = 0; r < 4; ++r) {
            const int bb = mt * 16 + q * 4 + r;
            x2[bb * H + n] = acc[mt][r] + ba;
        }
}

// ---------------------------------------------------------------------------
// K3 v8: single enc pass, spill-proof.  Full-K A tile (64 KB bf16) staged
// ONCE; n processed in 4 quarters of 128 with acc[4][2]=32 VGPR live per
// quarter (epilogued into val[4][4] then reused) -- R3's acc[4][8]=128 VGPR
// spilled accumulators to scratch (+55 us).  LDS 64+16=80 KB -> 2 blk/CU.
// red buffer aliases dead BsG.  grid 400.
// ---------------------------------------------------------------------------
__global__ __launch_bounds__(256) void k3_scores(
    const float* __restrict__ enc, const unsigned short* __restrict__ WhT,
    const float* __restrict__ x2, const float* __restrict__ v,
    float* __restrict__ part)
{
    __shared__ uint4 AsG[4096];    // 64 m x 64 kg (full K), XOR-swizzled, 64 KB
    __shared__ uint4 BsG[1024];    // 128 n x 8 kg (one kc chunk), 16 KB
    const int s    = blockIdx.x;
    const int tid  = threadIdx.x;
    const int wave = tid >> 6, lane = tid & 63;
    const int lrow = lane & 15, q = lane >> 4;

    // stage full A once: logical (m,kg) -> AsG[m*64 + (kg ^ (m&7))]
    const float* Abase = enc + (size_t)s * 64 * H;
    #pragma unroll
    for (int c = 0; c < 16; ++c) {
        int idx = c * 256 + tid;
        int m = idx >> 6, kg = idx & 63;
        const float* sa = Abase + m * H + kg * 8;
        AsG[m * 64 + (kg ^ (m & 7))] = pack8(ld4(sa), ld4(sa + 4));
    }

    float val[4][4];
    #pragma unroll
    for (int mt = 0; mt < 4; ++mt)
        #pragma unroll
        for (int r = 0; r < 4; ++r) val[mt][r] = 0.f;

    for (int nq = 0; nq < 4; ++nq) {
        const int n0 = nq * 128;
        floatx4 acc[4][2];
        #pragma unroll
        for (int mt = 0; mt < 4; ++mt)
            #pragma unroll
            for (int nt = 0; nt < 2; ++nt) acc[mt][nt] = (floatx4){0.f, 0.f, 0.f, 0.f};

        for (int kc = 0; kc < 8; ++kc) {
            __syncthreads();
            #pragma unroll
            for (int c = 0; c < 4; ++c) {
                int idx = c * 256 + tid;
                int n = idx >> 3, k8 = (idx & 7) ^ (n & 7);
                BsG[idx] = *(const uint4*)(WhT + (size_t)(n0 + n) * H + kc * 64 + k8 * 8);
            }
            __syncthreads();
            #pragma unroll
            for (int kk8 = 0; kk8 < 8; kk8 += 4) {
                const int k8 = kk8 + q;
                short8 a[4];
                #pragma unroll
                for (int mt = 0; mt < 4; ++mt) {
                    int m = mt * 16 + lrow;
                    a[mt] = *(const short8*)&AsG[m * 64 + kc * 8 + (k8 ^ (m & 7))];
                }
                #pragma unroll
                for (int nt = 0; nt < 2; ++nt) {
                    int n = wave * 32 + nt * 16 + lrow;
                    short8 bb = *(const short8*)&BsG[n * 8 + (k8 ^ (n & 7))];
                    #pragma unroll
                    for (int mt = 0; mt < 4; ++mt)
                        acc[mt][nt] = __builtin_amdgcn_mfma_f32_16x16x32_bf16(
                            a[mt], bb, acc[mt][nt], 0, 0, 0);
                }
            }
        }
        // quarter epilogue: fold into running val, free acc for next quarter
        #pragma unroll
        for (int mt = 0; mt < 4; ++mt)
            #pragma unroll
            for (int r = 0; r < 4; ++r) {
                const int bb = mt * 16 + q * 4 + r;
                #pragma unroll
                for (int nt = 0; nt < 2; ++nt) {
                    const int n = n0 + wave * 32 + nt * 16 + lrow;
                    val[mt][r] += tanhf(acc[mt][nt][r] + x2[bb * H + n]) * v[n];
                }
            }
    }

    // cross-lane (16-lane n-groups) then cross-wave reduction; red aliases BsG
    float* red = (float*)BsG;
    #pragma unroll
    for (int mt = 0; mt < 4; ++mt)
        #pragma unroll
        for (int r = 0; r < 4; ++r) {
            float sum = val[mt][r];
            #pragma unroll
            for (int off = 8; off > 0; off >>= 1) sum += __shfl_down(sum, off, 16);
            val[mt][r] = sum;
        }
    __syncthreads();
    if (lrow == 0) {
        #pragma unroll
        for (int mt = 0; mt < 4; ++mt)
            #pragma unroll
            for (int r = 0; r < 4; ++r)
                red[wave * 64 + mt * 16 + q * 4 + r] = val[mt][r];
    }
    __syncthreads();
    if (tid < 64) {
        float sc = red[tid] + red[64 + tid] + red[128 + tid] + red[192 + tid];
        part[(size_t)s * 64 + tid] = sc;
    }
}

// ---------------------------------------------------------------------------
// K45 fused: softmax (recomputed per block, sg==0 writes attn) + float4
// context partial.  grid (64 b, 8 sg), 128 threads.  (unchanged)
// ---------------------------------------------------------------------------
__global__ __launch_bounds__(128) void k45_ctx(
    const float* __restrict__ part, const float* __restrict__ enc,
    float* __restrict__ attn_out, float* __restrict__ ctxp)
{
    const int b  = blockIdx.x;
    const int sg = blockIdx.y;
    const int t  = threadIdx.x;
    __shared__ float a_all[SEQ];
    __shared__ float red2[2];
    __shared__ float smax, ssum;

    float mv[4];
    float mx = -1e30f;
    #pragma unroll
    for (int i = 0; i < 4; ++i) {
        int s = i * 128 + t;
        if (s < SEQ) {
            float vv = part[(size_t)s * 64 + b];
            mv[i] = vv;
            mx = fmaxf(mx, vv);
        }
    }
    #pragma unroll
    for (int off = 32; off > 0; off >>= 1) mx = fmaxf(mx, __shfl_down(mx, off, 64));
    if ((t & 63) == 0) red2[t >> 6] = mx;
    __syncthreads();
    if (t == 0) smax = fmaxf(red2[0], red2[1]);
    __syncthreads();
    float ev[4];
    float se = 0.f;
    #pragma unroll
    for (int i = 0; i < 4; ++i) {
        int s = i * 128 + t;
        if (s < SEQ) { ev[i] = expf(mv[i] - smax); se += ev[i]; }
    }
    #pragma unroll
    for (int off = 32; off > 0; off >>= 1) se += __shfl_down(se, off, 64);
    if ((t & 63) == 0) red2[t >> 6] = se;
    __syncthreads();
    if (t == 0) ssum = red2[0] + red2[1];
    __syncthreads();
    const float inv = 1.f / ssum;
    #pragma unroll
    for (int i = 0; i < 4; ++i) {
        int s = i * 128 + t;
        if (s < SEQ) {
            float av = ev[i] * inv;
            a_all[s] = av;
            if (sg == 0) attn_out[s * 64 + b] = av;
        }
    }
    __syncthreads();

    const int hh = 4 * t;
    const float* p = enc + ((size_t)(sg * 50) * 64 + b) * H + hh;
    float4 a0 = {0.f, 0.f, 0.f, 0.f}, a1 = {0.f, 0.f, 0.f, 0.f};
    #pragma unroll 5
    for (int i = 0; i < 50; i += 2) {
        float4 e0 = *(const float4*)p;
        float4 e1 = *(const float4*)(p + (size_t)64 * H);
        float w0 = a_all[sg * 50 + i];
        float w1 = a_all[sg * 50 + i + 1];
        a0.x += w0 * e0.x; a0.y += w0 * e0.y; a0.z += w0 * e0.z; a0.w += w0 * e0.w;
        a1.x += w1 * e1.x; a1.y += w1 * e1.y; a1.z += w1 * e1.z; a1.w += w1 * e1.w;
        p += (size_t)128 * H;
    }
    float4 r;
    r.x = a0.x + a1.x; r.y = a0.y + a1.y; r.z = a0.z + a1.z; r.w = a0.w + a1.w;
    *(float4*)&ctxp[((size_t)sg * 64 + b) * H + hh] = r;
}

// ---------------------------------------------------------------------------
// K5b: reduce 8 ctx partials; p = sigmoid(...); emit bf16 global_state.
// ---------------------------------------------------------------------------
__global__ __launch_bounds__(512) void k5b_p(
    const float* __restrict__ ctxp, const float* __restrict__ pWh,
    const float* __restrict__ hdec, const float* __restrict__ pWs,
    const float* __restrict__ x, const float* __restrict__ pWx,
    const float* __restrict__ pWx_b,
    float* __restrict__ p_out, float* __restrict__ p_ws,
    unsigned short* __restrict__ gsb)
{
    const int b = blockIdx.x;
    const int t = threadIdx.x;
    __shared__ float rbuf[8];
    float c = 0.f;
    #pragma unroll
    for (int sg = 0; sg < 8; ++sg)
        c += ctxp[((size_t)sg * 64 + b) * H + t];
    float hv = hdec[b * H + t];
    gsb[(size_t)b * H2 + t]     = (unsigned short)((__float_as_uint(hv) + 0x8000u) >> 16);
    gsb[(size_t)b * H2 + H + t] = (unsigned short)((__float_as_uint(c)  + 0x8000u) >> 16);
    float term = c * pWh[t] + hv * pWs[t] + x[b * H + t] * pWx[t];
    #pragma unroll
    for (int off = 32; off > 0; off >>= 1) term += __shfl_down(term, off, 64);
    if ((t & 63) == 0) rbuf[t >> 6] = term;
    __syncthreads();
    if (t == 0) {
        float ssv = pWx_b[0];
        #pragma unroll
        for (int w = 0; w < 8; ++w) ssv += rbuf[w];
        float pv = 1.f / (1.f + expf(-ssv));
        p_out[b] = pv;
        p_ws[b]  = pv;
    }
}

// ---------------------------------------------------------------------------
// K6: N=64 per block, grid 782 (+100 oov blocks).  (unchanged)
// ---------------------------------------------------------------------------
__global__ __launch_bounds__(256) void k6_vocab(
    const unsigned short* __restrict__ gsb, const float* __restrict__ outW,
    const float* __restrict__ outb, const float* __restrict__ p_ws,
    const float* __restrict__ attn, const int* __restrict__ mask,
    float* __restrict__ ext)
{
    const int tid = threadIdx.x;
    if (blockIdx.x >= NB_V) {
        int e = (blockIdx.x - NB_V) * 256 + tid;
        int s = e >> 6, b = e & 63;
        float val = (1.f - p_ws[b]) * attn[e] * (mask[e] ? 1.f : 0.f);
        ext[(size_t)b * EXT + V + s] = val;
        return;
    }
    __shared__ uint4 AsG[512];    // 64 b x 8 kg (bf16)
    __shared__ uint4 BsG[512];    // 64 v x 8 kg
    __shared__ float p_l[64];
    const int wave = tid >> 6, lane = tid & 63;
    const int lrow = lane & 15, q = lane >> 4;
    const int v0   = blockIdx.x * 64;

    if (tid < 64) p_l[tid] = p_ws[tid];

    floatx4 acc[4];
    #pragma unroll
    for (int mt = 0; mt < 4; ++mt) acc[mt] = (floatx4){0.f, 0.f, 0.f, 0.f};

    for (int kc = 0; kc < H2; kc += 64) {
        __syncthreads();
        #pragma unroll
        for (int c = 0; c < 2; ++c) {           // global_state tile (bf16 copy)
            int idx = c * 256 + tid;
            int m = idx >> 3, k8 = (idx & 7) ^ (m & 7);
            AsG[idx] = *(const uint4*)(gsb + (size_t)m * H2 + kc + k8 * 8);
        }
        #pragma unroll
        for (int c = 0; c < 2; ++c) {           // out_W tile (64 rows)
            int idx = c * 256 + tid;
            int n = idx >> 3, k8 = (idx & 7) ^ (n & 7);
            int vr = v0 + n; if (vr >= V) vr = V - 1;
            const float* sb = outW + (size_t)vr * H2 + kc + k8 * 8;
            BsG[idx] = pack8(ld4(sb), ld4(sb + 4));
        }
        __syncthreads();
        #pragma unroll
        for (int kk8 = 0; kk8 < 8; kk8 += 4) {
            const int k8 = kk8 + q;
            const int n = wave * 16 + lrow;
            short8 bb = *(const short8*)&BsG[n * 8 + (k8 ^ (n & 7))];
            #pragma unroll
            for (int mt = 0; mt < 4; ++mt) {
                int m = mt * 16 + lrow;
                short8 a = *(const short8*)&AsG[m * 8 + (k8 ^ (m & 7))];
                acc[mt] = __builtin_amdgcn_mfma_f32_16x16x32_bf16(a, bb, acc[mt], 0, 0, 0);
            }
        }
    }
    const int n = v0 + wave * 16 + lrow;
    if (n < V) {
        const float ob = outb[n];
        #pragma unroll
        for (int mt = 0; mt < 4; ++mt) {
            #pragma unroll
            for (int r = 0; r < 4; ++r) {
                const int bb = mt * 16 + q * 4 + r;
                float zz = acc[mt][r] + ob;
                float sv = (zz > 0.f) ? 1.0507009873554805f * zz
                                      : 1.7580993408473766f * (expf(zz) - 1.f);
                ext[(size_t)bb * EXT + n] = p_l[bb] * sv;
            }
        }
    }
}

// ---------------------------------------------------------------------------
extern "C" void kernel_launch(void* const* d_in, const int* in_sizes, int n_in,
                              void* d_out, int out_size, void* d_ws, size_t ws_size,
                              hipStream_t stream)
{
    (void)in_sizes; (void)n_in; (void)out_size; (void)ws_size;
    const float* x      = (const float*)d_in[0];
    const float* enc    = (const float*)d_in[1];
    const int*   mask   = (const int*)  d_in[2];
    const float* h0     = (const float*)d_in[3];
    const float* W_ih   = (const float*)d_in[4];
    const float* W_hh   = (const float*)d_in[5];
    const float* b_ih   = (const float*)d_in[6];
    const float* b_hh   = (const float*)d_in[7];
    const float* outW   = (const float*)d_in[8];
    const float* outb   = (const float*)d_in[9];
    const float* v      = (const float*)d_in[10];
    const float* Wh     = (const float*)d_in[11];
    const float* Ws     = (const float*)d_in[12];
    const float* b_attn = (const float*)d_in[13];
    const float* pWh    = (const float*)d_in[14];
    const float* pWs    = (const float*)d_in[15];
    const float* pWx    = (const float*)d_in[16];
    const float* pWx_b  = (const float*)d_in[17];

    float* out        = (float*)d_out;
    float* out_ext    = out;                           // 64 x 50400
    float* out_hidden = out + (size_t)64 * EXT;        // 64 x 512
    float* out_p      = out_hidden + 64 * H;           // 64
    float* out_attn   = out_p + 64;                    // 400 x 64

    float* ws       = (float*)d_ws;
    float* ws_x2    = ws;                              // 64*512
    float* ws_part  = ws_x2 + 64 * H;                  // 400*64 (single segment)
    float* ws_ctxp  = ws_part + 4 * SEQ * 64;          // 8*64*512
    float* ws_p     = ws_ctxp + 8 * 64 * H;            // 64
    float* ws_gacc  = ws_p + 64;                       // 6*8*64*512 (6.3MB)
    unsigned short* ws_whT = (unsigned short*)(ws_gacc + 6 * 8 * 64 * H);
    unsigned short* ws_wsT = ws_whT + (size_t)H * H;
    unsigned short* ws_gsb = ws_wsT + (size_t)H * H;   // 64 x 1024 bf16

    k01_fused<<<192, 256, 0, stream>>>(x, h0, W_ih, W_hh, ws_gacc,
                                       Wh, Ws, ws_whT, ws_wsT);
    k1_gru_fin<<<128, 256, 0, stream>>>(ws_gacc, h0, b_ih, b_hh, out_hidden);
    k2_x2<<<8, 256, 0, stream>>>(out_hidden, ws_wsT, b_attn, ws_x2);
    k3_scores<<<SEQ, 256, 0, stream>>>(enc, ws_whT, ws_x2, v, ws_part);
    k45_ctx<<<dim3(64, 8), 128, 0, stream>>>(ws_part, enc, out_attn, ws_ctxp);
    k5b_p<<<64, 512, 0, stream>>>(ws_ctxp, pWh, out_hidden, pWs, x, pWx, pWx_b,
                                  out_p, ws_p, ws_gsb);
    k6_vocab<<<NB_V + 100, 256, 0, stream>>>(ws_gsb, outW, outb, ws_p,
                                             out_attn, mask, out_ext);
}

// Round 5
// 448.466 us; speedup vs baseline: 1.1226x; 1.0121x over previous
//
#include <hip/hip_runtime.h>
#include <cmath>

#define H    512
#define H2   1024
#define V    50000
#define SEQ  400
#define EXT  (V + SEQ)   // 50400
#define NB_V 782         // ceil(50048/64); 782*64 = 50048 >= V

typedef __attribute__((ext_vector_type(8))) short short8;
typedef __attribute__((ext_vector_type(4))) float floatx4;

__device__ __forceinline__ unsigned int bfpack2(float lo, float hi) {
    unsigned int a = __float_as_uint(lo) + 0x8000u;   // round-half-up
    unsigned int b = __float_as_uint(hi) + 0x8000u;
    return __builtin_amdgcn_perm(b, a, 0x07060302);   // {hi.b3,hi.b2,lo.b3,lo.b2}
}
__device__ __forceinline__ uint4 pack8(float4 a, float4 b) {
    uint4 r;
    r.x = bfpack2(a.x, a.y);
    r.y = bfpack2(a.z, a.w);
    r.z = bfpack2(b.x, b.y);
    r.w = bfpack2(b.z, b.w);
    return r;
}
__device__ __forceinline__ float4 ld4(const float* p) { return *(const float4*)p; }

// ---------------------------------------------------------------------------
// K01 fused: blocks [0,64)  = GRU gate partials
//            blocks [64,192)= Wh/Ws transpose->bf16
// ---------------------------------------------------------------------------
__global__ __launch_bounds__(256) void k01_fused(
    const float* __restrict__ x, const float* __restrict__ h0,
    const float* __restrict__ W_ih, const float* __restrict__ W_hh,
    float* __restrict__ gacc,
    const float* __restrict__ Wh, const float* __restrict__ Ws,
    unsigned short* __restrict__ WhT, unsigned short* __restrict__ WsT)
{
    __shared__ __align__(16) unsigned char smem[65536];
    const int tid = threadIdx.x;

    if (blockIdx.x >= 64) {
        // ---- transpose branch ----
        float (*T)[65] = (float (*)[65])smem;          // 64*65*4 = 16.6 KB
        const int e   = blockIdx.x - 64;
        const int zz  = e >> 6, rem = e & 63;
        const int k0  = (rem & 7) * 64, n0 = (rem >> 3) * 64;
        const float* src = zz ? Ws : Wh;
        unsigned short* dst = zz ? WsT : WhT;
        #pragma unroll
        for (int i = 0; i < 16; ++i) {
            int ee = i * 256 + tid;
            int r = ee >> 6, c = ee & 63;
            T[r][c] = src[(size_t)(k0 + r) * H + n0 + c];
        }
        __syncthreads();
        #pragma unroll
        for (int i = 0; i < 16; ++i) {
            int ee = i * 256 + tid;
            int nn = ee >> 6, kk = ee & 63;
            unsigned int u = __float_as_uint(T[kk][nn]) + 0x8000u;
            dst[(size_t)(n0 + nn) * H + k0 + kk] = (unsigned short)(u >> 16);
        }
        return;
    }

    // ---- GRU partials branch ----
    uint4* Ax = (uint4*)smem;                       // 512 uint4 = 8 KB
    uint4* Ah = (uint4*)(smem + 8192);              // 8 KB
    uint4 (*Bg)[512] = (uint4 (*)[512])(smem + 16384);  // 6 x 8 KB
    const int wave = tid >> 6, lane = tid & 63;
    const int lrow = lane & 15, q = lane >> 4;
    const int jb = blockIdx.x & 7, ks = blockIdx.x >> 3;
    const int J0 = jb * 64;
    const int kc = ks * 64;

    #pragma unroll
    for (int c = 0; c < 2; ++c) {
        int idx = c * 256 + tid;
        int m = idx >> 3, j2 = idx & 7, k8 = j2 ^ (m & 7);
        const float* sx = x  + m * H + kc + k8 * 8;
        const float* sh = h0 + m * H + kc + k8 * 8;
        Ax[idx] = pack8(ld4(sx), ld4(sx + 4));
        Ah[idx] = pack8(ld4(sh), ld4(sh + 4));
    }
    #pragma unroll
    for (int g = 0; g < 6; ++g) {
        const float* Wb = (g < 3) ? W_ih : W_hh;
        const int go = (g % 3) * H;
        #pragma unroll
        for (int c = 0; c < 2; ++c) {
            int idx = c * 256 + tid;
            int n = idx >> 3, j2 = idx & 7, k8 = j2 ^ (n & 7);
            const float* sw = Wb + (size_t)(go + J0 + n) * H + kc + k8 * 8;
            Bg[g][idx] = pack8(ld4(sw), ld4(sw + 4));
        }
    }
    __syncthreads();

    floatx4 accm[6][4];
    #pragma unroll
    for (int g = 0; g < 6; ++g)
        #pragma unroll
        for (int mt = 0; mt < 4; ++mt) accm[g][mt] = (floatx4){0.f, 0.f, 0.f, 0.f};

    #pragma unroll
    for (int kk8 = 0; kk8 < 8; kk8 += 4) {
        const int k8 = kk8 + q;
        short8 ax[4], ah[4];
        #pragma unroll
        for (int mt = 0; mt < 4; ++mt) {
            int m = mt * 16 + lrow;
            ax[mt] = *(const short8*)&Ax[m * 8 + (k8 ^ (m & 7))];
            ah[mt] = *(const short8*)&Ah[m * 8 + (k8 ^ (m & 7))];
        }
        const int n = wave * 16 + lrow;
        const int gidx = n * 8 + (k8 ^ (n & 7));
        #pragma unroll
        for (int g = 0; g < 6; ++g) {
            short8 bb = *(const short8*)&Bg[g][gidx];
            #pragma unroll
            for (int mt = 0; mt < 4; ++mt)
                accm[g][mt] = __builtin_amdgcn_mfma_f32_16x16x32_bf16(
                    (g < 3) ? ax[mt] : ah[mt], bb, accm[g][mt], 0, 0, 0);
        }
    }
    const int j = J0 + wave * 16 + lrow;
    #pragma unroll
    for (int g = 0; g < 6; ++g)
        #pragma unroll
        for (int mt = 0; mt < 4; ++mt)
            #pragma unroll
            for (int r = 0; r < 4; ++r) {
                const int bb = mt * 16 + q * 4 + r;
                gacc[(((size_t)g * 8 + ks) * 64 + bb) * H + j] = accm[g][mt][r];
            }
}

// ---------------------------------------------------------------------------
// K1b: reduce k-slices, apply GRU gate math.
// ---------------------------------------------------------------------------
__global__ __launch_bounds__(256) void k1_gru_fin(
    const float* __restrict__ gacc, const float* __restrict__ h0,
    const float* __restrict__ b_ih, const float* __restrict__ b_hh,
    float* __restrict__ h_out)
{
    const int e = blockIdx.x * 256 + threadIdx.x;
    const int j = e & (H - 1);
    const int b = e >> 9;
    float gs[6];
    #pragma unroll
    for (int g = 0; g < 6; ++g) {
        float sum = 0.f;
        #pragma unroll
        for (int ks = 0; ks < 8; ++ks)
            sum += gacc[(((size_t)g * 8 + ks) * 64 + b) * H + j];
        gs[g] = sum;
    }
    float rg = 1.f / (1.f + expf(-(gs[0] + b_ih[j] + gs[3] + b_hh[j])));
    float zg = 1.f / (1.f + expf(-(gs[1] + b_ih[H + j] + gs[4] + b_hh[H + j])));
    float ng = tanhf(gs[2] + b_ih[2 * H + j] + rg * (gs[5] + b_hh[2 * H + j]));
    float h0v = h0[b * H + j];
    h_out[b * H + j] = (1.f - zg) * ng + zg * h0v;
}

// ---------------------------------------------------------------------------
// K2 (MFMA): x2 = h @ Ws + b_attn.
// ---------------------------------------------------------------------------
__global__ __launch_bounds__(256) void k2_x2(
    const float* __restrict__ h, const unsigned short* __restrict__ WsT,
    const float* __restrict__ b_attn, float* __restrict__ x2)
{
    __shared__ uint4 Ag[512];
    __shared__ uint4 Bgg[512];
    const int tid  = threadIdx.x;
    const int wave = tid >> 6, lane = tid & 63;
    const int lrow = lane & 15, q = lane >> 4;
    const int n0   = blockIdx.x * 64;

    floatx4 acc[4];
    #pragma unroll
    for (int mt = 0; mt < 4; ++mt) acc[mt] = (floatx4){0.f, 0.f, 0.f, 0.f};

    for (int kc = 0; kc < H; kc += 64) {
        __syncthreads();
        #pragma unroll
        for (int c = 0; c < 2; ++c) {
            int idx = c * 256 + tid;
            int m = idx >> 3, j2 = idx & 7, k8 = j2 ^ (m & 7);
            const float* sh = h + m * H + kc + k8 * 8;
            Ag[idx] = pack8(ld4(sh), ld4(sh + 4));
            Bgg[idx] = *(const uint4*)(WsT + (size_t)(n0 + m) * H + kc + k8 * 8);
        }
        __syncthreads();
        #pragma unroll
        for (int kk8 = 0; kk8 < 8; kk8 += 4) {
            const int k8 = kk8 + q;
            const int n = wave * 16 + lrow;
            short8 bb = *(const short8*)&Bgg[n * 8 + (k8 ^ (n & 7))];
            #pragma unroll
            for (int mt = 0; mt < 4; ++mt) {
                int m = mt * 16 + lrow;
                short8 a = *(const short8*)&Ag[m * 8 + (k8 ^ (m & 7))];
                acc[mt] = __builtin_amdgcn_mfma_f32_16x16x32_bf16(a, bb, acc[mt], 0, 0, 0);
            }
        }
    }
    const int n = n0 + wave * 16 + lrow;
    const float ba = b_attn[n];
    #pragma unroll
    for (int mt = 0; mt < 4; ++mt)
        #pragma unroll
        for (int r = 0; r < 4; ++r) {
            const int bb = mt * 16 + q * 4 + r;
            x2[bb * H + n] = acc[mt][r] + ba;
        }
}

// ---------------------------------------------------------------------------
// K3 (R2-best): N=256 per block, grid (400,2).  enc re-read is L3-served
// (enc = 52.4 MB < 256 MB Infinity Cache), so the 2-pass split costs ~nothing
// at HBM while keeping 41 KB LDS -> 3 blocks/CU and 16 barriers/block.
// Single-pass variants measured WORSE: R3 acc[4][8] spilled (+55 us);
// R4 full-K A-tile (80 KB LDS, 64 barriers, 400-block tail) +5 us.
// ---------------------------------------------------------------------------
__global__ __launch_bounds__(256) void k3_scores(
    const float* __restrict__ enc, const unsigned short* __restrict__ WhT,
    const float* __restrict__ x2, const float* __restrict__ v,
    float* __restrict__ part)
{
    __shared__ uint4 AsG[512];    // 64 m  x 8 kg
    __shared__ uint4 BsG[2048];   // 256 n x 8 kg  (32 KB)
    __shared__ float red[256];
    const int s   = blockIdx.x;
    const int nc  = blockIdx.y;
    const int n0  = nc * 256;
    const int tid  = threadIdx.x;
    const int wave = tid >> 6, lane = tid & 63;
    const int lrow = lane & 15, q = lane >> 4;

    floatx4 acc[4][4];
    #pragma unroll
    for (int mt = 0; mt < 4; ++mt)
        #pragma unroll
        for (int nt = 0; nt < 4; ++nt) acc[mt][nt] = (floatx4){0.f, 0.f, 0.f, 0.f};

    const float* Abase = enc + (size_t)s * 64 * H;
    for (int kc = 0; kc < H; kc += 64) {
        __syncthreads();
        #pragma unroll
        for (int c = 0; c < 2; ++c) {
            int idx = c * 256 + tid;
            int m = idx >> 3, k8 = (idx & 7) ^ (m & 7);
            const float* sa = Abase + m * H + kc + k8 * 8;
            AsG[idx] = pack8(ld4(sa), ld4(sa + 4));
        }
        #pragma unroll
        for (int c = 0; c < 8; ++c) {
            int idx = c * 256 + tid;
            int n = idx >> 3, k8 = (idx & 7) ^ (n & 7);
            BsG[idx] = *(const uint4*)(WhT + (size_t)(n0 + n) * H + kc + k8 * 8);
        }
        __syncthreads();
        #pragma unroll
        for (int kk8 = 0; kk8 < 8; kk8 += 4) {
            const int k8 = kk8 + q;
            short8 a[4], b[4];
            #pragma unroll
            for (int mt = 0; mt < 4; ++mt) {
                int m = mt * 16 + lrow;
                a[mt] = *(const short8*)&AsG[m * 8 + (k8 ^ (m & 7))];
            }
            #pragma unroll
            for (int nt = 0; nt < 4; ++nt) {
                int n = wave * 64 + nt * 16 + lrow;
                b[nt] = *(const short8*)&BsG[n * 8 + (k8 ^ (n & 7))];
            }
            #pragma unroll
            for (int mt = 0; mt < 4; ++mt)
                #pragma unroll
                for (int nt = 0; nt < 4; ++nt)
                    acc[mt][nt] = __builtin_amdgcn_mfma_f32_16x16x32_bf16(
                        a[mt], b[nt], acc[mt][nt], 0, 0, 0);
        }
    }
    float val[4][4];
    #pragma unroll
    for (int mt = 0; mt < 4; ++mt) {
        #pragma unroll
        for (int r = 0; r < 4; ++r) {
            const int bb = mt * 16 + q * 4 + r;
            float sum = 0.f;
            #pragma unroll
            for (int nt = 0; nt < 4; ++nt) {
                const int n = n0 + wave * 64 + nt * 16 + lrow;
                sum += tanhf(acc[mt][nt][r] + x2[bb * H + n]) * v[n];
            }
            #pragma unroll
            for (int off = 8; off > 0; off >>= 1) sum += __shfl_down(sum, off, 16);
            val[mt][r] = sum;
        }
    }
    __syncthreads();
    if (lrow == 0) {
        #pragma unroll
        for (int mt = 0; mt < 4; ++mt)
            #pragma unroll
            for (int r = 0; r < 4; ++r)
                red[wave * 64 + mt * 16 + q * 4 + r] = val[mt][r];
    }
    __syncthreads();
    if (tid < 64) {
        float sc = red[tid] + red[64 + tid] + red[128 + tid] + red[192 + tid];
        part[((size_t)nc * SEQ + s) * 64 + tid] = sc;
    }
}

// ---------------------------------------------------------------------------
// K45 fused: per-(b,sg) block recomputes the 400-wide softmax redundantly,
// sg==0 writes attn; then float4-vectorized context partial (50 s rows).
// grid (64 b, 8 sg), 128 threads.
// ---------------------------------------------------------------------------
__global__ __launch_bounds__(128) void k45_ctx(
    const float* __restrict__ part, const float* __restrict__ enc,
    float* __restrict__ attn_out, float* __restrict__ ctxp)
{
    const int b  = blockIdx.x;
    const int sg = blockIdx.y;
    const int t  = threadIdx.x;
    __shared__ float a_all[SEQ];
    __shared__ float red2[2];
    __shared__ float smax, ssum;

    float mv[4];
    float mx = -1e30f;
    #pragma unroll
    for (int i = 0; i < 4; ++i) {
        int s = i * 128 + t;
        if (s < SEQ) {
            float vv = part[(size_t)s * 64 + b] + part[((size_t)SEQ + s) * 64 + b];
            mv[i] = vv;
            mx = fmaxf(mx, vv);
        }
    }
    #pragma unroll
    for (int off = 32; off > 0; off >>= 1) mx = fmaxf(mx, __shfl_down(mx, off, 64));
    if ((t & 63) == 0) red2[t >> 6] = mx;
    __syncthreads();
    if (t == 0) smax = fmaxf(red2[0], red2[1]);
    __syncthreads();
    float ev[4];
    float se = 0.f;
    #pragma unroll
    for (int i = 0; i < 4; ++i) {
        int s = i * 128 + t;
        if (s < SEQ) { ev[i] = expf(mv[i] - smax); se += ev[i]; }
    }
    #pragma unroll
    for (int off = 32; off > 0; off >>= 1) se += __shfl_down(se, off, 64);
    if ((t & 63) == 0) red2[t >> 6] = se;
    __syncthreads();
    if (t == 0) ssum = red2[0] + red2[1];
    __syncthreads();
    const float inv = 1.f / ssum;
    #pragma unroll
    for (int i = 0; i < 4; ++i) {
        int s = i * 128 + t;
        if (s < SEQ) {
            float av = ev[i] * inv;
            a_all[s] = av;
            if (sg == 0) attn_out[s * 64 + b] = av;
        }
    }
    __syncthreads();

    const int hh = 4 * t;
    const float* p = enc + ((size_t)(sg * 50) * 64 + b) * H + hh;
    float4 a0 = {0.f, 0.f, 0.f, 0.f}, a1 = {0.f, 0.f, 0.f, 0.f};
    #pragma unroll 5
    for (int i = 0; i < 50; i += 2) {
        float4 e0 = *(const float4*)p;
        float4 e1 = *(const float4*)(p + (size_t)64 * H);
        float w0 = a_all[sg * 50 + i];
        float w1 = a_all[sg * 50 + i + 1];
        a0.x += w0 * e0.x; a0.y += w0 * e0.y; a0.z += w0 * e0.z; a0.w += w0 * e0.w;
        a1.x += w1 * e1.x; a1.y += w1 * e1.y; a1.z += w1 * e1.z; a1.w += w1 * e1.w;
        p += (size_t)128 * H;
    }
    float4 r;
    r.x = a0.x + a1.x; r.y = a0.y + a1.y; r.z = a0.z + a1.z; r.w = a0.w + a1.w;
    *(float4*)&ctxp[((size_t)sg * 64 + b) * H + hh] = r;
}

// ---------------------------------------------------------------------------
// K5b: reduce 8 ctx partials; p = sigmoid(...); emit bf16 global_state.
// ---------------------------------------------------------------------------
__global__ __launch_bounds__(512) void k5b_p(
    const float* __restrict__ ctxp, const float* __restrict__ pWh,
    const float* __restrict__ hdec, const float* __restrict__ pWs,
    const float* __restrict__ x, const float* __restrict__ pWx,
    const float* __restrict__ pWx_b,
    float* __restrict__ p_out, float* __restrict__ p_ws,
    unsigned short* __restrict__ gsb)
{
    const int b = blockIdx.x;
    const int t = threadIdx.x;
    __shared__ float rbuf[8];
    float c = 0.f;
    #pragma unroll
    for (int sg = 0; sg < 8; ++sg)
        c += ctxp[((size_t)sg * 64 + b) * H + t];
    float hv = hdec[b * H + t];
    gsb[(size_t)b * H2 + t]     = (unsigned short)((__float_as_uint(hv) + 0x8000u) >> 16);
    gsb[(size_t)b * H2 + H + t] = (unsigned short)((__float_as_uint(c)  + 0x8000u) >> 16);
    float term = c * pWh[t] + hv * pWs[t] + x[b * H + t] * pWx[t];
    #pragma unroll
    for (int off = 32; off > 0; off >>= 1) term += __shfl_down(term, off, 64);
    if ((t & 63) == 0) rbuf[t >> 6] = term;
    __syncthreads();
    if (t == 0) {
        float ssv = pWx_b[0];
        #pragma unroll
        for (int w = 0; w < 8; ++w) ssv += rbuf[w];
        float pv = 1.f / (1.f + expf(-ssv));
        p_out[b] = pv;
        p_ws[b]  = pv;
    }
}

// ---------------------------------------------------------------------------
// K6: N=64 per block, grid 782 (+100 oov blocks).
// ---------------------------------------------------------------------------
__global__ __launch_bounds__(256) void k6_vocab(
    const unsigned short* __restrict__ gsb, const float* __restrict__ outW,
    const float* __restrict__ outb, const float* __restrict__ p_ws,
    const float* __restrict__ attn, const int* __restrict__ mask,
    float* __restrict__ ext)
{
    const int tid = threadIdx.x;
    if (blockIdx.x >= NB_V) {
        int e = (blockIdx.x - NB_V) * 256 + tid;
        int s = e >> 6, b = e & 63;
        float val = (1.f - p_ws[b]) * attn[e] * (mask[e] ? 1.f : 0.f);
        ext[(size_t)b * EXT + V + s] = val;
        return;
    }
    __shared__ uint4 AsG[512];    // 64 b x 8 kg (bf16)
    __shared__ uint4 BsG[512];    // 64 v x 8 kg
    __shared__ float p_l[64];
    const int wave = tid >> 6, lane = tid & 63;
    const int lrow = lane & 15, q = lane >> 4;
    const int v0   = blockIdx.x * 64;

    if (tid < 64) p_l[tid] = p_ws[tid];

    floatx4 acc[4];
    #pragma unroll
    for (int mt = 0; mt < 4; ++mt) acc[mt] = (floatx4){0.f, 0.f, 0.f, 0.f};

    for (int kc = 0; kc < H2; kc += 64) {
        __syncthreads();
        #pragma unroll
        for (int c = 0; c < 2; ++c) {           // global_state tile (bf16 copy)
            int idx = c * 256 + tid;
            int m = idx >> 3, k8 = (idx & 7) ^ (m & 7);
            AsG[idx] = *(const uint4*)(gsb + (size_t)m * H2 + kc + k8 * 8);
        }
        #pragma unroll
        for (int c = 0; c < 2; ++c) {           // out_W tile (64 rows)
            int idx = c * 256 + tid;
            int n = idx >> 3, k8 = (idx & 7) ^ (n & 7);
            int vr = v0 + n; if (vr >= V) vr = V - 1;
            const float* sb = outW + (size_t)vr * H2 + kc + k8 * 8;
            BsG[idx] = pack8(ld4(sb), ld4(sb + 4));
        }
        __syncthreads();
        #pragma unroll
        for (int kk8 = 0; kk8 < 8; kk8 += 4) {
            const int k8 = kk8 + q;
            const int n = wave * 16 + lrow;
            short8 bb = *(const short8*)&BsG[n * 8 + (k8 ^ (n & 7))];
            #pragma unroll
            for (int mt = 0; mt < 4; ++mt) {
                int m = mt * 16 + lrow;
                short8 a = *(const short8*)&AsG[m * 8 + (k8 ^ (m & 7))];
                acc[mt] = __builtin_amdgcn_mfma_f32_16x16x32_bf16(a, bb, acc[mt], 0, 0, 0);
            }
        }
    }
    const int n = v0 + wave * 16 + lrow;
    if (n < V) {
        const float ob = outb[n];
        #pragma unroll
        for (int mt = 0; mt < 4; ++mt) {
            #pragma unroll
            for (int r = 0; r < 4; ++r) {
                const int bb = mt * 16 + q * 4 + r;
                float zz = acc[mt][r] + ob;
                float sv = (zz > 0.f) ? 1.0507009873554805f * zz
                                      : 1.7580993408473766f * (expf(zz) - 1.f);
                ext[(size_t)bb * EXT + n] = p_l[bb] * sv;
            }
        }
    }
}

// ---------------------------------------------------------------------------
extern "C" void kernel_launch(void* const* d_in, const int* in_sizes, int n_in,
                              void* d_out, int out_size, void* d_ws, size_t ws_size,
                              hipStream_t stream)
{
    (void)in_sizes; (void)n_in; (void)out_size; (void)ws_size;
    const float* x      = (const float*)d_in[0];
    const float* enc    = (const float*)d_in[1];
    const int*   mask   = (const int*)  d_in[2];
    const float* h0     = (const float*)d_in[3];
    const float* W_ih   = (const float*)d_in[4];
    const float* W_hh   = (const float*)d_in[5];
    const float* b_ih   = (const float*)d_in[6];
    const float* b_hh   = (const float*)d_in[7];
    const float* outW   = (const float*)d_in[8];
    const float* outb   = (const float*)d_in[9];
    const float* v      = (const float*)d_in[10];
    const float* Wh     = (const float*)d_in[11];
    const float* Ws     = (const float*)d_in[12];
    const float* b_attn = (const float*)d_in[13];
    const float* pWh    = (const float*)d_in[14];
    const float* pWs    = (const float*)d_in[15];
    const float* pWx    = (const float*)d_in[16];
    const float* pWx_b  = (const float*)d_in[17];

    float* out        = (float*)d_out;
    float* out_ext    = out;                           // 64 x 50400
    float* out_hidden = out + (size_t)64 * EXT;        // 64 x 512
    float* out_p      = out_hidden + 64 * H;           // 64
    float* out_attn   = out_p + 64;                    // 400 x 64

    float* ws       = (float*)d_ws;
    float* ws_x2    = ws;                              // 64*512
    float* ws_part  = ws_x2 + 64 * H;                  // 2*400*64
    float* ws_ctxp  = ws_part + 4 * SEQ * 64;          // 8*64*512
    float* ws_p     = ws_ctxp + 8 * 64 * H;            // 64
    float* ws_gacc  = ws_p + 64;                       // 6*8*64*512 (6.3MB)
    unsigned short* ws_whT = (unsigned short*)(ws_gacc + 6 * 8 * 64 * H);
    unsigned short* ws_wsT = ws_whT + (size_t)H * H;
    unsigned short* ws_gsb = ws_wsT + (size_t)H * H;   // 64 x 1024 bf16

    k01_fused<<<192, 256, 0, stream>>>(x, h0, W_ih, W_hh, ws_gacc,
                                       Wh, Ws, ws_whT, ws_wsT);
    k1_gru_fin<<<128, 256, 0, stream>>>(ws_gacc, h0, b_ih, b_hh, out_hidden);
    k2_x2<<<8, 256, 0, stream>>>(out_hidden, ws_wsT, b_attn, ws_x2);
    k3_scores<<<dim3(SEQ, 2), 256, 0, stream>>>(enc, ws_whT, ws_x2, v, ws_part);
    k45_ctx<<<dim3(64, 8), 128, 0, stream>>>(ws_part, enc, out_attn, ws_ctxp);
    k5b_p<<<64, 512, 0, stream>>>(ws_ctxp, pWh, out_hidden, pWs, x, pWx, pWx_b,
                                  out_p, ws_p, ws_gsb);
    k6_vocab<<<NB_V + 100, 256, 0, stream>>>(ws_gsb, outW, outb, ws_p,
                                             out_attn, mask, out_ext);
}